// Round 6
// baseline (363.437 us; speedup 1.0000x reference)
//
#include <hip/hip_runtime.h>
#include <hip/hip_bf16.h>
#include <hip/hip_fp8.h>
#include <stdint.h>

#define N_ROWS 8192
#define DIM    768          // elements per row; == BYTES per row in fp8
#define BM     256
#define BN     256
#define BKB    128          // K-tile bytes (= fp8 elements)
#define KTILES (DIM / BKB)  // 6
#define NT2    (N_ROWS / BN)
#define LDS_BYTES 131072

typedef __attribute__((ext_vector_type(4))) int   i32x4;
typedef __attribute__((ext_vector_type(8))) int   i32x8;
typedef __attribute__((ext_vector_type(4))) float f32x4;

__device__ __forceinline__ float tstudent(float c) {
    // (1 + 0.5*(1-c))^{-1.5} = t^{-1.5}, t = 1.5 - 0.5c
    float t = 1.5f - 0.5f * c;
    float r = rsqrtf(t);
    return r * r * r;
}
__device__ __forceinline__ uint8_t f2fp8(float x) {
    __hip_fp8_e4m3 q(x);        // OCP e4m3fn, RNE saturating
    return (uint8_t)q.__x;
}

// ---------------- kernel 1: row L2-normalize fp32 -> fp8 e4m3, fused fp32 diag numerator ----------------
__global__ __launch_bounds__(256) void norm_kernel(const float* __restrict__ z1,
                                                   const float* __restrict__ z2,
                                                   uint8_t* __restrict__ n1,
                                                   uint8_t* __restrict__ n2,
                                                   float* __restrict__ num) {
    int row = blockIdx.x;
    int t = threadIdx.x;
    const float* s1 = z1 + (size_t)row * DIM;
    const float* s2 = z2 + (size_t)row * DIM;
    float a0 = s1[t], a1 = s1[t + 256], a2 = s1[t + 512];
    float b0 = s2[t], b1 = s2[t + 256], b2 = s2[t + 512];
    float ss1 = a0 * a0 + a1 * a1 + a2 * a2;
    float ss2 = b0 * b0 + b1 * b1 + b2 * b2;
    float sd  = a0 * b0 + a1 * b1 + a2 * b2;
    for (int off = 32; off; off >>= 1) {
        ss1 += __shfl_down(ss1, off);
        ss2 += __shfl_down(ss2, off);
        sd  += __shfl_down(sd, off);
    }
    __shared__ float w1[4], w2[4], wd[4];
    __shared__ float sc1_s, sc2_s;
    if ((t & 63) == 0) { int wi = t >> 6; w1[wi] = ss1; w2[wi] = ss2; wd[wi] = sd; }
    __syncthreads();
    if (t == 0) {
        float nrm1 = fmaxf(sqrtf(w1[0] + w1[1] + w1[2] + w1[3]), 1e-8f);
        float nrm2 = fmaxf(sqrtf(w2[0] + w2[1] + w2[2] + w2[3]), 1e-8f);
        float dot  = wd[0] + wd[1] + wd[2] + wd[3];
        sc1_s = 1.0f / nrm1;
        sc2_s = 1.0f / nrm2;
        num[row] = tstudent(dot / (nrm1 * nrm2));   // numerator in fp32 — no fp8 error
    }
    __syncthreads();
    float sc1 = sc1_s, sc2 = sc2_s;
    uint8_t* d1 = n1 + (size_t)row * DIM;
    uint8_t* d2 = n2 + (size_t)row * DIM;
    d1[t]       = f2fp8(a0 * sc1);
    d1[t + 256] = f2fp8(a1 * sc1);
    d1[t + 512] = f2fp8(a2 * sc1);
    d2[t]       = f2fp8(b0 * sc2);
    d2[t + 256] = f2fp8(b1 * sc2);
    d2[t + 512] = f2fp8(b2 * sc2);
}

// ---------------- kernel 2: 256x256 8-wave MX-FP8 (K=128) MFMA GEMM ----------------
// LDS: [A buf0 32K][A buf1 32K][B buf0 32K][B buf1 32K] = 128 KiB.
// Tile: 256 rows x 128 B (fp8, BK=128). SAME row stride / swizzle / staging as the
// bf16-BK64 version: 16B-granule g stored at g ^ (row & 7); global_load_lds keeps a
// linear LDS dest with inverse-swizzled global source column.
// MFMA: mfma_scale_f32_16x16x128_f8f6f4, fmt fp8/fp8, all scales = 1.0 (0x7F bytes)
//   -> plain fp8 GEMM at 2x bf16 rate. A/B frag: lane row = l&15, 32 k-bytes at
//   (l>>4)*32; loaded as two b128 (unswizzled into registers, so any uniform HW
//   k-permutation cancels between A and B; C/D layout is shape-determined).
// Schedule = round-5 pipelined read-ahead, ledger identical:
//   stage order B0,B1 | B2,B3 | A0,A2 | A1,A3 (2/phase); VMW(4)@ph1, VMW(2)@ph3.
//   A-quad q reads mb {2q,2q+1}: q0,q1 -> j0/j2 (early-A), q2,q3 -> j1/j3 (late-A).

__device__ __forceinline__ void stG(const uint8_t* g, char* lds, int t, int j) {
    __builtin_amdgcn_global_load_lds(
        (const __attribute__((address_space(1))) void*)(g + (size_t)j * 64 * DIM),
        (__attribute__((address_space(3))) void*)(lds + t * 16 + j * 8192), 16, 0, 0);
}

#define BAR()  asm volatile("s_barrier" ::: "memory")
#define VMW(n) asm volatile("s_waitcnt vmcnt(" #n ")" ::: "memory")

#define MFMA_SC(A, B, C) __builtin_amdgcn_mfma_scale_f32_16x16x128_f8f6f4( \
        (A), (B), (C), 0, 0, 0, 0x7F7F7F7F, 0, 0x7F7F7F7F)

#define READ_AF(dst, Abase, mb) {                                               \
    const char* _p = (Abase) + rbA + (mb) * 2048;                               \
    i32x4 _lo = *(const i32x4*)(_p + ga0);                                      \
    i32x4 _hi = *(const i32x4*)(_p + (ga0 ^ 16));                               \
    dst = (i32x8){_lo[0], _lo[1], _lo[2], _lo[3], _hi[0], _hi[1], _hi[2], _hi[3]}; }

#define READ_AQ(set, Abase, q)                                                  \
    READ_AF(set[0], Abase, (q)*2)                                               \
    READ_AF(set[1], Abase, (q)*2 + 1)

#define READ_BLO(dst, Bbase)                                                    \
    _Pragma("unroll")                                                           \
    for (int n = 0; n < 4; ++n)                                                 \
        dst[n] = *(const i32x4*)((Bbase) + rbB + n * 2048 + ga0);

#define BUILD_BFRAG(BLO, Bbase)                                                 \
    _Pragma("unroll")                                                           \
    for (int n = 0; n < 4; ++n) {                                               \
        i32x4 _hi = *(const i32x4*)((Bbase) + rbB + n * 2048 + (ga0 ^ 16));     \
        bfrag[n] = (i32x8){BLO[n][0], BLO[n][1], BLO[n][2], BLO[n][3],          \
                           _hi[0], _hi[1], _hi[2], _hi[3]};                     \
    }

#define MFMA_Q(q, AS)                                                           \
    __builtin_amdgcn_s_setprio(1);                                              \
    _Pragma("unroll")                                                           \
    for (int n = 0; n < 4; ++n) {                                               \
        acc[(q)*2][n]     = MFMA_SC(AS[0], bfrag[n], acc[(q)*2][n]);            \
        acc[(q)*2 + 1][n] = MFMA_SC(AS[1], bfrag[n], acc[(q)*2 + 1][n]);        \
    }                                                                           \
    __builtin_amdgcn_s_setprio(0);

#define TILE(kt, BLOC, BLON, PAR) {                                             \
    const char* Ab  = smem + (PAR) * 32768;                                     \
    const char* Bb  = smem + 65536 + (PAR) * 32768;                             \
    const char* AbN = smem + ((PAR) ^ 1) * 32768;                               \
    const char* BbN = smem + 65536 + ((PAR) ^ 1) * 32768;                       \
    char* AnW = smem + ((PAR) ^ 1) * 32768;                                     \
    char* BnW = smem + 65536 + ((PAR) ^ 1) * 32768;                             \
    const uint8_t* Agn = Ag + ((kt) + 1) * BKB;                                 \
    const uint8_t* Bgn = Bg + ((kt) + 1) * BKB;                                 \
    /* ph0 */                                                                   \
    stG(Bgn, BnW, t, 0); stG(Bgn, BnW, t, 1);                                   \
    BUILD_BFRAG(BLOC, Bb);                                                      \
    READ_AQ(aS1, Ab, 1);                                                        \
    MFMA_Q(0, aS0);                                                             \
    /* ph1 */                                                                   \
    stG(Bgn, BnW, t, 2); stG(Bgn, BnW, t, 3);                                   \
    VMW(4); BAR();                                                              \
    READ_AQ(aS0, Ab, 2);                                                        \
    MFMA_Q(1, aS1);                                                             \
    /* ph2 */                                                                   \
    stG(Agn, AnW, t, 0); stG(Agn, AnW, t, 2);                                   \
    READ_AQ(aS1, Ab, 3);                                                        \
    MFMA_Q(2, aS0);                                                             \
    /* ph3 */                                                                   \
    stG(Agn, AnW, t, 1); stG(Agn, AnW, t, 3);                                   \
    VMW(2); BAR();                                                              \
    READ_BLO(BLON, BbN);                                                        \
    READ_AQ(aS0, AbN, 0);                                                       \
    MFMA_Q(3, aS1);                                                             \
}

__global__ __launch_bounds__(512, 2) void gemm_kernel(const uint8_t* __restrict__ n1,
                                                      const uint8_t* __restrict__ n2,
                                                      float* __restrict__ partial) {
    extern __shared__ char smem[];
    int t = threadIdx.x;
    int l = t & 63;
    int w = t >> 6;
    int wr = w >> 2;   // 0..1 -> A half (128 rows)
    int wc = w & 3;    // 0..3 -> B quarter (64 cols)

    // XCD-aware + L2 supertile mapping (1024 blocks, bijective)
    int bid = blockIdx.x;
    int xcd = bid & 7, idx = bid >> 3;
    int br = xcd * 4 + (idx & 3);
    int bc = (idx >> 4) * 4 + ((idx >> 2) & 3);
    int rowbase = br * BM, colbase = bc * BN;

    // staging: thread t covers LDS rows (t>>3)+64j, granule t&7;
    // inverse-swizzled global 16B-granule = (t&7) ^ ((t>>3)&7)
    int sr = t >> 3;
    int gcol0 = ((t & 7) ^ (sr & 7)) * 16;
    const uint8_t* Ag = n1 + (size_t)(rowbase + sr) * DIM + gcol0;
    const uint8_t* Bg = n2 + (size_t)(colbase + sr) * DIM + gcol0;

    f32x4 acc[8][4] = {};

    // read-side: lane's 32 k-bytes = true granules {2h, 2h+1}, h = l>>4, stored at
    // granule ^ (row&7) with row&7 == l&7  ->  unswizzled reconstruction in regs.
    int ga0 = ((2 * (l >> 4)) ^ (l & 7)) * 16;
    int rbA = (wr * 128 + (l & 15)) * 128;
    int rbB = (wc * 64 + (l & 15)) * 128;

    i32x8 aS0[2], aS1[2];
    i32x4 bLoA[4], bLoB[4];
    i32x8 bfrag[4];

    // prologue: stage K-tile 0 into buf0 (B0..B3, A0, A2, A1, A3)
    {
        char* A0b = smem;
        char* B0b = smem + 65536;
        stG(Bg, B0b, t, 0); stG(Bg, B0b, t, 1); stG(Bg, B0b, t, 2); stG(Bg, B0b, t, 3);
        stG(Ag, A0b, t, 0); stG(Ag, A0b, t, 2); stG(Ag, A0b, t, 1); stG(Ag, A0b, t, 3);
    }
    VMW(2);   // drains B0-3, A0, A2; leaves [A1,A3] in flight (pipeline invariant)
    BAR();
    READ_BLO(bLoA, smem + 65536);
    READ_AQ(aS0, smem, 0);

    TILE(0, bLoA, bLoB, 0)
    TILE(1, bLoB, bLoA, 1)
    TILE(2, bLoA, bLoB, 0)
    TILE(3, bLoB, bLoA, 1)
    TILE(4, bLoA, bLoB, 0)
    {   // peeled tile 5 (parity 1, B-lo prefetched in bLoB; no staging)
        const char* Ab = smem + 32768;
        const char* Bb = smem + 65536 + 32768;
        /* ph0 */
        BUILD_BFRAG(bLoB, Bb);
        READ_AQ(aS1, Ab, 1);
        MFMA_Q(0, aS0);
        /* ph1 — drain late-A of this tile before q2 reads */
        VMW(0); BAR();
        READ_AQ(aS0, Ab, 2);
        MFMA_Q(1, aS1);
        /* ph2 */
        READ_AQ(aS1, Ab, 3);
        MFMA_Q(2, aS0);
        /* ph3 */
        MFMA_Q(3, aS1);
    }

    // ---------------- epilogue: t-Student + row sums ----------------
    // C/D map: row = wr*128 + m*16 + (l>>4)*4 + j, col = wc*64 + n*16 + (l&15)
    float* red = (float*)smem;
    __syncthreads();
    #pragma unroll
    for (int m = 0; m < 8; ++m) {
        #pragma unroll
        for (int j = 0; j < 4; ++j) {
            float s = 0.f;
            #pragma unroll
            for (int n = 0; n < 4; ++n) s += tstudent(acc[m][n][j]);
            s += __shfl_xor(s, 1);
            s += __shfl_xor(s, 2);
            s += __shfl_xor(s, 4);
            s += __shfl_xor(s, 8);
            if ((l & 15) == 0) {
                int row = wr * 128 + m * 16 + (l >> 4) * 4 + j;
                red[row * 4 + wc] = s;
            }
        }
    }
    __syncthreads();
    if (t < BM) {
        partial[(size_t)bc * N_ROWS + rowbase + t] = red[t * 4 + 0] + red[t * 4 + 1] + red[t * 4 + 2] + red[t * 4 + 3];
    }
}

// ---------------- kernel 3: per-row denom + ratio, per-block sums ----------------
__global__ __launch_bounds__(256) void reduce_kernel(const float* __restrict__ partial,
                                                     const float* __restrict__ num,
                                                     float* __restrict__ blocksum) {
    int row = blockIdx.x * 256 + threadIdx.x;
    float d = 0.f;
    #pragma unroll 8
    for (int ct = 0; ct < NT2; ++ct) d += partial[(size_t)ct * N_ROWS + row];
    float s = num[row] / d;
    for (int off = 32; off; off >>= 1) s += __shfl_down(s, off);
    __shared__ float wsum[4];
    if ((threadIdx.x & 63) == 0) wsum[threadIdx.x >> 6] = s;
    __syncthreads();
    if (threadIdx.x == 0) blocksum[blockIdx.x] = wsum[0] + wsum[1] + wsum[2] + wsum[3];
}

// ---------------- kernel 4: final scalar ----------------
__global__ __launch_bounds__(64) void final_kernel(const float* __restrict__ blocksum,
                                                   float* __restrict__ out) {
    int l = threadIdx.x;
    float s = (l < 32) ? blocksum[l] : 0.f;
    for (int off = 32; off; off >>= 1) s += __shfl_down(s, off);
    if (l == 0) out[0] = -(s / (float)N_ROWS);
}

extern "C" void kernel_launch(void* const* d_in, const int* in_sizes, int n_in,
                              void* d_out, int out_size, void* d_ws, size_t ws_size,
                              hipStream_t stream) {
    const float* z1 = (const float*)d_in[0];
    const float* z2 = (const float*)d_in[1];
    char* ws = (char*)d_ws;
    const size_t n_bytes = (size_t)N_ROWS * DIM;   // 6,291,456 (fp8)
    uint8_t* n1 = (uint8_t*)ws;
    uint8_t* n2 = (uint8_t*)(ws + n_bytes);
    float* num      = (float*)(ws + 2 * n_bytes);                     // 32 KB
    float* partial  = (float*)(ws + 2 * n_bytes + 32768);             // 1 MB used
    float* blocksum = (float*)(ws + 2 * n_bytes + 32768 + 2097152);   // 128 B

    hipFuncSetAttribute((const void*)gemm_kernel,
                        hipFuncAttributeMaxDynamicSharedMemorySize, LDS_BYTES);

    norm_kernel<<<N_ROWS, 256, 0, stream>>>(z1, z2, n1, n2, num);
    gemm_kernel<<<NT2 * NT2, 512, LDS_BYTES, stream>>>(n1, n2, partial);
    reduce_kernel<<<N_ROWS / 256, 256, 0, stream>>>(partial, num, blocksum);
    final_kernel<<<1, 64, 0, stream>>>(blocksum, (float*)d_out);
}

// Round 7
// 355.915 us; speedup vs baseline: 1.0211x; 1.0211x over previous
//
#include <hip/hip_runtime.h>
#include <hip/hip_bf16.h>
#include <hip/hip_fp8.h>
#include <stdint.h>

#define N_ROWS 8192
#define DIM    768          // elements per row; == BYTES per row in fp8
#define BM     256
#define BN     256
#define BKB    128          // K-tile bytes (= fp8 elements)
#define KTILES (DIM / BKB)  // 6
#define NT2    (N_ROWS / BN)
#define LDS_BYTES 131072

typedef __attribute__((ext_vector_type(4))) int   i32x4;
typedef __attribute__((ext_vector_type(8))) int   i32x8;
typedef __attribute__((ext_vector_type(4))) float f32x4;

__device__ __forceinline__ float tstudent(float c) {
    // (1 + 0.5*(1-c))^{-1.5} = t^{-1.5}, t = 1.5 - 0.5c
    float t = 1.5f - 0.5f * c;
    float r = rsqrtf(t);
    return r * r * r;
}
__device__ __forceinline__ uint8_t f2fp8(float x) {
    __hip_fp8_e4m3 q(x);        // OCP e4m3fn, RNE saturating
    return (uint8_t)q.__x;
}

// ---------------- kernel 1: row L2-normalize fp32 -> fp8 e4m3, fused fp32 diag numerator ----------------
__global__ __launch_bounds__(256) void norm_kernel(const float* __restrict__ z1,
                                                   const float* __restrict__ z2,
                                                   uint8_t* __restrict__ n1,
                                                   uint8_t* __restrict__ n2,
                                                   float* __restrict__ num) {
    int row = blockIdx.x;
    int t = threadIdx.x;
    const float* s1 = z1 + (size_t)row * DIM;
    const float* s2 = z2 + (size_t)row * DIM;
    float a0 = s1[t], a1 = s1[t + 256], a2 = s1[t + 512];
    float b0 = s2[t], b1 = s2[t + 256], b2 = s2[t + 512];
    float ss1 = a0 * a0 + a1 * a1 + a2 * a2;
    float ss2 = b0 * b0 + b1 * b1 + b2 * b2;
    float sd  = a0 * b0 + a1 * b1 + a2 * b2;
    for (int off = 32; off; off >>= 1) {
        ss1 += __shfl_down(ss1, off);
        ss2 += __shfl_down(ss2, off);
        sd  += __shfl_down(sd, off);
    }
    __shared__ float w1[4], w2[4], wd[4];
    __shared__ float sc1_s, sc2_s;
    if ((t & 63) == 0) { int wi = t >> 6; w1[wi] = ss1; w2[wi] = ss2; wd[wi] = sd; }
    __syncthreads();
    if (t == 0) {
        float nrm1 = fmaxf(sqrtf(w1[0] + w1[1] + w1[2] + w1[3]), 1e-8f);
        float nrm2 = fmaxf(sqrtf(w2[0] + w2[1] + w2[2] + w2[3]), 1e-8f);
        float dot  = wd[0] + wd[1] + wd[2] + wd[3];
        sc1_s = 1.0f / nrm1;
        sc2_s = 1.0f / nrm2;
        num[row] = tstudent(dot / (nrm1 * nrm2));   // numerator in fp32 — no fp8 error
    }
    __syncthreads();
    float sc1 = sc1_s, sc2 = sc2_s;
    uint8_t* d1 = n1 + (size_t)row * DIM;
    uint8_t* d2 = n2 + (size_t)row * DIM;
    d1[t]       = f2fp8(a0 * sc1);
    d1[t + 256] = f2fp8(a1 * sc1);
    d1[t + 512] = f2fp8(a2 * sc1);
    d2[t]       = f2fp8(b0 * sc2);
    d2[t + 256] = f2fp8(b1 * sc2);
    d2[t + 512] = f2fp8(b2 * sc2);
}

// ---------------- kernel 2: 256x256 8-wave MX-FP8 (K=128) MFMA GEMM, low-pressure JIT reads ----------------
// LDS: [A buf0 32K][A buf1 32K][B buf0 32K][B buf1 32K] = 128 KiB.
// Tile: 256 rows x 128 B (fp8, BK=128). 16B-granule g stored at g ^ (row & 7);
// global_load_lds keeps linear LDS dest + inverse-swizzled global source column.
// MFMA: mfma_scale_f32_16x16x128_f8f6f4, fp8/fp8, scales = 1.0 (0x7F bytes).
// Lane fragment: row l&15, 32 k-bytes = true granules {2h, 2h+1}, h = l>>4, stored
// at (2h)^r and (2h)^r^1 (r = l&7) -> two b128 at ga0 / ga0^16, combined with
// __builtin_shufflevector (pure SSA, no alloca/scratch risk — R6 lesson).
// Any uniform k-permutation cancels between A and B (same lane mapping both sides).
//
// JIT schedule (round-7): fragments read in the phase that uses them (no read-ahead
// register ping-pong — R6's spill cause). Live vectors: bfrag[4]=32 + aq[2]=16 regs.
// Stage order for tile kt+1 during kt: ph0:B0,B1  ph1:B2,B3  ph2:A0,A2  ph3:A1,A3.
// Per-wave vmcnt ledger (steady state, entering ph0: [A1,A3(kt)] in flight):
//   ph1: +B2B3 -> 6; VMW(4) drains A1,A3(kt) (= late-A, needed by ph2/ph3 reads); BAR.
//   ph3: +A1A3(kt+1) -> 8; VMW(2) drains B0-3 + A0,A2(kt+1) (needed by next ph0); BAR.
// WAR: buffer overwritten in kt was last read in kt-1, >=1 barrier earlier. Safe.

__device__ __forceinline__ void stG(const uint8_t* g, char* lds, int t, int j) {
    __builtin_amdgcn_global_load_lds(
        (const __attribute__((address_space(1))) void*)(g + (size_t)j * 64 * DIM),
        (__attribute__((address_space(3))) void*)(lds + t * 16 + j * 8192), 16, 0, 0);
}

#define BAR()  asm volatile("s_barrier" ::: "memory")
#define VMW(n) asm volatile("s_waitcnt vmcnt(" #n ")" ::: "memory")

#define MFMA_SC(A, B, C) __builtin_amdgcn_mfma_scale_f32_16x16x128_f8f6f4( \
        (A), (B), (C), 0, 0, 0, 0x7F7F7F7F, 0, 0x7F7F7F7F)

#define READ_FRAG(dst, p) {                                                     \
    i32x4 _lo = *(const i32x4*)((p) + ga0);                                     \
    i32x4 _hi = *(const i32x4*)((p) + (ga0 ^ 16));                              \
    dst = __builtin_shufflevector(_lo, _hi, 0, 1, 2, 3, 4, 5, 6, 7);            \
}

#define READ_AQ(q)                                                              \
    READ_FRAG(aq[0], Ab + rbA + ((q)*2    ) * 2048)                             \
    READ_FRAG(aq[1], Ab + rbA + ((q)*2 + 1) * 2048)

#define READ_BALL()                                                             \
    READ_FRAG(bfrag[0], Bb + rbB + 0 * 2048)                                    \
    READ_FRAG(bfrag[1], Bb + rbB + 1 * 2048)                                    \
    READ_FRAG(bfrag[2], Bb + rbB + 2 * 2048)                                    \
    READ_FRAG(bfrag[3], Bb + rbB + 3 * 2048)

#define MFMA_Q(q)                                                               \
    __builtin_amdgcn_s_setprio(1);                                              \
    _Pragma("unroll")                                                           \
    for (int n = 0; n < 4; ++n) {                                               \
        acc[(q)*2][n]     = MFMA_SC(aq[0], bfrag[n], acc[(q)*2][n]);            \
        acc[(q)*2 + 1][n] = MFMA_SC(aq[1], bfrag[n], acc[(q)*2 + 1][n]);        \
    }                                                                           \
    __builtin_amdgcn_s_setprio(0);

__global__ __launch_bounds__(512, 2) void gemm_kernel(const uint8_t* __restrict__ n1,
                                                      const uint8_t* __restrict__ n2,
                                                      float* __restrict__ partial) {
    extern __shared__ char smem[];
    int t = threadIdx.x;
    int l = t & 63;
    int w = t >> 6;
    int wr = w >> 2;   // 0..1 -> A half (128 rows)
    int wc = w & 3;    // 0..3 -> B quarter (64 cols)

    // XCD-aware + L2 supertile mapping (1024 blocks, bijective)
    int bid = blockIdx.x;
    int xcd = bid & 7, idx = bid >> 3;
    int br = xcd * 4 + (idx & 3);
    int bc = (idx >> 4) * 4 + ((idx >> 2) & 3);
    int rowbase = br * BM, colbase = bc * BN;

    // staging: thread t covers LDS rows (t>>3)+64j, granule t&7;
    // inverse-swizzled global 16B-granule = (t&7) ^ ((t>>3)&7)
    int sr = t >> 3;
    int gcol0 = ((t & 7) ^ (sr & 7)) * 16;
    const uint8_t* Ag = n1 + (size_t)(rowbase + sr) * DIM + gcol0;
    const uint8_t* Bg = n2 + (size_t)(colbase + sr) * DIM + gcol0;

    f32x4 acc[8][4] = {};

    int ga0 = ((2 * (l >> 4)) ^ (l & 7)) * 16;
    int rbA = (wr * 128 + (l & 15)) * 128;
    int rbB = (wc * 64 + (l & 15)) * 128;

    i32x8 aq[2];
    i32x8 bfrag[4];

    // prologue: stage K-tile 0 into buf0 (B0..B3, A0, A2, A1, A3)
    {
        char* A0b = smem;
        char* B0b = smem + 65536;
        stG(Bg, B0b, t, 0); stG(Bg, B0b, t, 1); stG(Bg, B0b, t, 2); stG(Bg, B0b, t, 3);
        stG(Ag, A0b, t, 0); stG(Ag, A0b, t, 2); stG(Ag, A0b, t, 1); stG(Ag, A0b, t, 3);
    }
    VMW(2);   // drains B0-3, A0, A2; leaves [A1,A3] in flight (pipeline invariant)
    BAR();

    for (int kt = 0; kt < KTILES - 1; ++kt) {
        int db = kt & 1;
        const char* Ab = smem + db * 32768;
        const char* Bb = smem + 65536 + db * 32768;
        char* AnW = smem + (db ^ 1) * 32768;
        char* BnW = smem + 65536 + (db ^ 1) * 32768;
        const uint8_t* Agn = Ag + (kt + 1) * BKB;
        const uint8_t* Bgn = Bg + (kt + 1) * BKB;

        /* ph0 */
        stG(Bgn, BnW, t, 0); stG(Bgn, BnW, t, 1);
        READ_BALL();
        READ_AQ(0);
        MFMA_Q(0);
        /* ph1 */
        stG(Bgn, BnW, t, 2); stG(Bgn, BnW, t, 3);
        VMW(4); BAR();        // publish late-A(kt) for ph2/ph3
        READ_AQ(1);
        MFMA_Q(1);
        /* ph2 */
        stG(Agn, AnW, t, 0); stG(Agn, AnW, t, 2);
        READ_AQ(2);
        MFMA_Q(2);
        /* ph3 */
        stG(Agn, AnW, t, 1); stG(Agn, AnW, t, 3);
        VMW(2); BAR();        // publish B(kt+1) + early-A(kt+1) for next ph0
        READ_AQ(3);
        MFMA_Q(3);
    }
    {   // peeled last tile (kt = 5, parity 1; no staging)
        const char* Ab = smem + 32768;
        const char* Bb = smem + 65536 + 32768;
        /* ph0 */
        READ_BALL();
        READ_AQ(0);
        MFMA_Q(0);
        /* ph1 — drain late-A of this tile before ph2 reads it */
        VMW(0); BAR();
        READ_AQ(1);
        MFMA_Q(1);
        /* ph2 */
        READ_AQ(2);
        MFMA_Q(2);
        /* ph3 */
        READ_AQ(3);
        MFMA_Q(3);
    }

    // ---------------- epilogue: t-Student + row sums ----------------
    // C/D map: row = wr*128 + m*16 + (l>>4)*4 + j, col = wc*64 + n*16 + (l&15)
    float* red = (float*)smem;
    __syncthreads();
    #pragma unroll
    for (int m = 0; m < 8; ++m) {
        #pragma unroll
        for (int j = 0; j < 4; ++j) {
            float s = 0.f;
            #pragma unroll
            for (int n = 0; n < 4; ++n) s += tstudent(acc[m][n][j]);
            s += __shfl_xor(s, 1);
            s += __shfl_xor(s, 2);
            s += __shfl_xor(s, 4);
            s += __shfl_xor(s, 8);
            if ((l & 15) == 0) {
                int row = wr * 128 + m * 16 + (l >> 4) * 4 + j;
                red[row * 4 + wc] = s;
            }
        }
    }
    __syncthreads();
    if (t < BM) {
        partial[(size_t)bc * N_ROWS + rowbase + t] = red[t * 4 + 0] + red[t * 4 + 1] + red[t * 4 + 2] + red[t * 4 + 3];
    }
}

// ---------------- kernel 3: per-row denom + ratio, per-block sums ----------------
__global__ __launch_bounds__(256) void reduce_kernel(const float* __restrict__ partial,
                                                     const float* __restrict__ num,
                                                     float* __restrict__ blocksum) {
    int row = blockIdx.x * 256 + threadIdx.x;
    float d = 0.f;
    #pragma unroll 8
    for (int ct = 0; ct < NT2; ++ct) d += partial[(size_t)ct * N_ROWS + row];
    float s = num[row] / d;
    for (int off = 32; off; off >>= 1) s += __shfl_down(s, off);
    __shared__ float wsum[4];
    if ((threadIdx.x & 63) == 0) wsum[threadIdx.x >> 6] = s;
    __syncthreads();
    if (threadIdx.x == 0) blocksum[blockIdx.x] = wsum[0] + wsum[1] + wsum[2] + wsum[3];
}

// ---------------- kernel 4: final scalar ----------------
__global__ __launch_bounds__(64) void final_kernel(const float* __restrict__ blocksum,
                                                   float* __restrict__ out) {
    int l = threadIdx.x;
    float s = (l < 32) ? blocksum[l] : 0.f;
    for (int off = 32; off; off >>= 1) s += __shfl_down(s, off);
    if (l == 0) out[0] = -(s / (float)N_ROWS);
}

extern "C" void kernel_launch(void* const* d_in, const int* in_sizes, int n_in,
                              void* d_out, int out_size, void* d_ws, size_t ws_size,
                              hipStream_t stream) {
    const float* z1 = (const float*)d_in[0];
    const float* z2 = (const float*)d_in[1];
    char* ws = (char*)d_ws;
    const size_t n_bytes = (size_t)N_ROWS * DIM;   // 6,291,456 (fp8)
    uint8_t* n1 = (uint8_t*)ws;
    uint8_t* n2 = (uint8_t*)(ws + n_bytes);
    float* num      = (float*)(ws + 2 * n_bytes);                     // 32 KB
    float* partial  = (float*)(ws + 2 * n_bytes + 32768);             // 1 MB used
    float* blocksum = (float*)(ws + 2 * n_bytes + 32768 + 2097152);   // 128 B

    hipFuncSetAttribute((const void*)gemm_kernel,
                        hipFuncAttributeMaxDynamicSharedMemorySize, LDS_BYTES);

    norm_kernel<<<N_ROWS, 256, 0, stream>>>(z1, z2, n1, n2, num);
    gemm_kernel<<<NT2 * NT2, 512, LDS_BYTES, stream>>>(n1, n2, partial);
    reduce_kernel<<<N_ROWS / 256, 256, 0, stream>>>(partial, num, blocksum);
    final_kernel<<<1, 64, 0, stream>>>(blocksum, (float*)d_out);
}